// Round 4
// baseline (869.733 us; speedup 1.0000x reference)
//
#include <hip/hip_runtime.h>
#include <math.h>

// ---------------- problem constants ----------------
#define NROWS 48000
#define DIM   256
#define KCB   1024
#define GK    64
#define TM    128     // rows per block in K1 (4 waves x 32 rows)
#define NCH   64      // chunks of 16 codes

// ---------------- workspace byte offsets ----------------
#define WS_SCNT    0u         // int[1024]
#define WS_GSUM    4096u      // float[64]
#define WS_GCNT    4352u      // float[64]
#define WS_OFFS    4608u      // int[1024]
#define WS_CURS    8704u      // int[1024]
#define WS_ROWCODE 12800u     // int[48000]
#define WS_BUCKET  204800u    // int[48000]
#define WS_CBHI    396800u    // _Float16[1024*256] swizzled (512 KB)
#define WS_CBLO    921088u    // _Float16[1024*256] swizzled (512 KB)
#define WS_ZERO_BYTES 4608u

// ---------------- output element offsets ----------------
#define OUT_SHAPE 12288000
#define OUT_GAIN  12550144
#define OUT_SNUM  12550208
#define OUT_GNUM  12551232

typedef _Float16 half8  __attribute__((ext_vector_type(8)));
typedef float    f32x4  __attribute__((ext_vector_type(4)));

// K0: split fp32 codebook into f16 hi/lo planes, pre-swizzled into MFMA
// B-fragment order for 16-code chunks so each (chunk,kk) fragment is one
// contiguous, perfectly-coalesced 1024 B wave-load.
// dst(halfs) = ch*4096 + kk*512 + lc*32 + lq*8 + e
// where code = ch*16+lc, k = kk*32 + lq*8 + e.
__global__ __launch_bounds__(256) void k_convert_cb(const float* __restrict__ cb,
                                                    _Float16* __restrict__ hi,
                                                    _Float16* __restrict__ lo) {
    int i = blockIdx.x * 256 + threadIdx.x;   // 262144 total
    float v = cb[i];
    int code = i >> 8, k = i & 255;
    int ch = code >> 4, lc = code & 15;
    int kk = k >> 5, lq = (k & 31) >> 3, e = k & 7;
    int dst = ch * 4096 + kk * 512 + lc * 32 + lq * 8 + e;
    _Float16 h = (_Float16)v;
    hi[dst] = h;
    lo[dst] = (_Float16)(v - (float)h);
}

// K1: barrier-free K-loop. B streams global(L2)->VGPR; A cached in VGPRs;
// no LDS in the hot loop (LDS only for tiny per-row result arrays).
__global__ __launch_bounds__(256, 2) void k_main(
    const float* __restrict__ x, const float* __restrict__ cb,
    const float* __restrict__ gcb,
    const _Float16* __restrict__ cbh, const _Float16* __restrict__ cbl,
    int* __restrict__ ws_scnt, float* __restrict__ ws_gsum,
    float* __restrict__ ws_gcnt, int* __restrict__ ws_rowcode,
    float* __restrict__ out_q) {
    __shared__ float gl[GK];
    __shared__ int   shInd[TM];
    __shared__ float shGq[TM];
    __shared__ float shLg[TM];
    const int tid = threadIdx.x;
    const int w = tid >> 6, lane = tid & 63;
    const int lc = lane & 15, lq = lane >> 4;
    const int row0 = blockIdx.x * TM;

    if (tid < GK) gl[tid] = gcb[tid];

    // ---- load + convert A fragments: 2 sets of 16 rows per wave ----
    half8 afh[2][8], afl[2][8];
#pragma unroll
    for (int s = 0; s < 2; ++s) {
        const float* rp = x + (long)(row0 + w * 32 + s * 16 + lc) * DIM + lq * 8;
#pragma unroll
        for (int kk = 0; kk < 8; ++kk) {
            float4 v0 = *(const float4*)(rp + kk * 32);
            float4 v1 = *(const float4*)(rp + kk * 32 + 4);
            _Float16 h0 = (_Float16)v0.x, h1 = (_Float16)v0.y,
                     h2 = (_Float16)v0.z, h3 = (_Float16)v0.w;
            _Float16 h4 = (_Float16)v1.x, h5 = (_Float16)v1.y,
                     h6 = (_Float16)v1.z, h7 = (_Float16)v1.w;
            afh[s][kk] = (half8){h0, h1, h2, h3, h4, h5, h6, h7};
            afl[s][kk] = (half8){(_Float16)(v0.x - (float)h0), (_Float16)(v0.y - (float)h1),
                                 (_Float16)(v0.z - (float)h2), (_Float16)(v0.w - (float)h3),
                                 (_Float16)(v1.x - (float)h4), (_Float16)(v1.y - (float)h5),
                                 (_Float16)(v1.z - (float)h6), (_Float16)(v1.w - (float)h7)};
        }
    }

    float vmax[2][4];
    int   vidx[2][4];
#pragma unroll
    for (int s = 0; s < 2; ++s)
#pragma unroll
        for (int r = 0; r < 4; ++r) { vmax[s][r] = -1e30f; vidx[s][r] = 0; }

    // ---- K-loop: 64 chunks of 16 codes, no barriers ----
    const half8* pH = (const half8*)(cbh + lc * 32 + lq * 8);   // + ch*512 + kk*64 (half8 units)
    const half8* pL = (const half8*)(cbl + lc * 32 + lq * 8);
    for (int ch = 0; ch < NCH; ++ch) {
        half8 bh[8], bl[8];
#pragma unroll
        for (int kk = 0; kk < 8; ++kk) {
            bh[kk] = pH[ch * 512 + kk * 64];
            bl[kk] = pL[ch * 512 + kk * 64];
        }
        f32x4 a0[2], a1[2], a2[2];
#pragma unroll
        for (int s = 0; s < 2; ++s) {
            a0[s] = (f32x4){0, 0, 0, 0};
            a1[s] = (f32x4){0, 0, 0, 0};
            a2[s] = (f32x4){0, 0, 0, 0};
        }
#pragma unroll
        for (int kk = 0; kk < 8; ++kk) {
#pragma unroll
            for (int s = 0; s < 2; ++s) {
                a0[s] = __builtin_amdgcn_mfma_f32_16x16x32_f16(afh[s][kk], bh[kk], a0[s], 0, 0, 0);
                a1[s] = __builtin_amdgcn_mfma_f32_16x16x32_f16(afl[s][kk], bh[kk], a1[s], 0, 0, 0);
                a2[s] = __builtin_amdgcn_mfma_f32_16x16x32_f16(afh[s][kk], bl[kk], a2[s], 0, 0, 0);
            }
        }
        int code = ch * 16 + lc;
#pragma unroll
        for (int s = 0; s < 2; ++s)
#pragma unroll
            for (int r = 0; r < 4; ++r) {
                float dv = a0[s][r] + a1[s][r] + a2[s][r];
                if (dv > vmax[s][r]) { vmax[s][r] = dv; vidx[s][r] = code; }
            }
    }

    // ---- argmax reduce across the 16-lane col (lc) dimension ----
#pragma unroll
    for (int m = 1; m < 16; m <<= 1) {
#pragma unroll
        for (int s = 0; s < 2; ++s)
#pragma unroll
            for (int r = 0; r < 4; ++r) {
                float ov = __shfl_xor(vmax[s][r], m, 64);
                int   oi = __shfl_xor(vidx[s][r], m, 64);
                if (ov > vmax[s][r] || (ov == vmax[s][r] && oi < vidx[s][r])) {
                    vmax[s][r] = ov; vidx[s][r] = oi;
                }
            }
    }
    if (lc == 0) {
#pragma unroll
        for (int s = 0; s < 2; ++s)
#pragma unroll
            for (int r = 0; r < 4; ++r) {
                int lrow = w * 32 + s * 16 + lq * 4 + r;
                shLg[lrow]  = vmax[s][r];
                shInd[lrow] = vidx[s][r];
            }
    }
    __syncthreads();

    // ---- parallel gain quantization: lane j evaluates level j ----
    {
        float glv = gl[lane];
        for (int i = 0; i < 32; ++i) {
            int row = w * 32 + i;
            float gv = shLg[row];
            float lg = logf(fmaxf(gv, 1e-5f));
            float d = lg - glv; d = d * d;
            int gi = lane;
#pragma unroll
            for (int m = 1; m < 64; m <<= 1) {
                float od = __shfl_xor(d, m, 64);
                int   og = __shfl_xor(gi, m, 64);
                if (od < d || (od == d && og < gi)) { d = od; gi = og; }
            }
            if (lane == i) {
                float gsel = gl[gi];
                shGq[row] = expf(gsel);
                int sidx = shInd[row];
                ws_rowcode[row0 + row] = sidx;
                atomicAdd(ws_scnt + sidx, 1);
                atomicAdd(ws_gsum + gi, lg);
                atomicAdd(ws_gcnt + gi, 1.0f);
            }
        }
    }
    __syncthreads();

    // ---- epilogue: quantize = exp(gain_q) * cb[code] ----
    {
        float4* qv = (float4*)(out_q + (long)row0 * DIM);
#pragma unroll
        for (int it = 0; it < 32; ++it) {
            int idx = it * 256 + tid;       // 8192 float4s
            int r = idx >> 6, c4 = idx & 63;
            int code = shInd[r];
            float gq = shGq[r];
            const float4 cbv = *(const float4*)(cb + code * DIM + c4 * 4);
            float4 o;
            o.x = gq * cbv.x; o.y = gq * cbv.y; o.z = gq * cbv.z; o.w = gq * cbv.w;
            qv[idx] = o;
        }
    }
}

// K2a: exclusive prefix scan of code counts -> bucket offsets + cursors
__global__ __launch_bounds__(1024) void k_scan(const int* __restrict__ scnt,
                                               int* __restrict__ offs,
                                               int* __restrict__ curs) {
    int t = threadIdx.x;
    __shared__ int sc[1024];
    int my = scnt[t];
    sc[t] = my;
    __syncthreads();
    for (int d = 1; d < 1024; d <<= 1) {
        int v = (t >= d) ? sc[t - d] : 0;
        __syncthreads();
        sc[t] += v;
        __syncthreads();
    }
    int ex = sc[t] - my;
    offs[t] = ex;
    curs[t] = ex;
}

// K2b: scatter row ids into code-sorted buckets
__global__ __launch_bounds__(256) void k_scatter(const int* __restrict__ rowcode,
                                                 int* __restrict__ curs,
                                                 int* __restrict__ bucket) {
    int i = blockIdx.x * 256 + threadIdx.x;
    if (i < NROWS) {
        int code = rowcode[i];
        int pos = atomicAdd(curs + code, 1);
        bucket[pos] = i;
    }
}

// K2c: per-code column reduction of x + full shape/gain finalize
__global__ __launch_bounds__(256) void k_reduce(
    const float* __restrict__ x, const float* __restrict__ cb,
    const float* __restrict__ gcb, const float* __restrict__ snum,
    const float* __restrict__ gnum,
    const int* __restrict__ scnt, const int* __restrict__ offs,
    const int* __restrict__ bucket,
    const float* __restrict__ gsum, const float* __restrict__ gcnt,
    float* __restrict__ out) {
    int b = blockIdx.x, t = threadIdx.x;
    if (b < KCB) {
        int cnt = scnt[b], base = offs[b];
        float s = 0.0f;
        int i = 0;
        for (; i + 4 <= cnt; i += 4) {
            int r0 = bucket[base + i], r1 = bucket[base + i + 1];
            int r2 = bucket[base + i + 2], r3 = bucket[base + i + 3];
            float v0 = x[r0 * DIM + t], v1 = x[r1 * DIM + t];
            float v2 = x[r2 * DIM + t], v3 = x[r3 * DIM + t];
            s += v0 + v1 + v2 + v3;
        }
        for (; i < cnt; ++i) {
            int r = bucket[base + i];
            s += x[r * DIM + t];
        }
        __shared__ float red[4];
        int w = t >> 6;
        float v = s * s;
#pragma unroll
        for (int m = 32; m; m >>= 1) v += __shfl_xor(v, m, 64);
        if ((t & 63) == 0) red[w] = v;
        __syncthreads();
        float tot = red[0] + red[1] + red[2] + red[3];
        float sn = s / fmaxf(sqrtf(tot), 1e-5f);
        float u = cb[b * DIM + t] * 0.99f + 0.01f * sn;
        __syncthreads();
        v = u * u;
#pragma unroll
        for (int m = 32; m; m >>= 1) v += __shfl_xor(v, m, 64);
        if ((t & 63) == 0) red[w] = v;
        __syncthreads();
        tot = red[0] + red[1] + red[2] + red[3];
        out[OUT_SHAPE + b * DIM + t] = u / fmaxf(sqrtf(tot), 1e-12f);
        if (t == 0) out[OUT_SNUM + b] = snum[b] * 0.99f + 0.01f * (float)cnt;
    } else if (t < GK) {
        float cnt = gcnt[t];
        float gn  = gsum[t] / fmaxf(cnt, 1e-5f);
        out[OUT_GAIN + t] = gcb[t] * 0.99f + 0.01f * gn;
        out[OUT_GNUM + t] = gnum[t] * 0.99f + 0.01f * cnt;
    }
}

extern "C" void kernel_launch(void* const* d_in, const int* in_sizes, int n_in,
                              void* d_out, int out_size, void* d_ws, size_t ws_size,
                              hipStream_t stream) {
    const float* x    = (const float*)d_in[0];
    const float* cb   = (const float*)d_in[1];
    const float* gcb  = (const float*)d_in[2];
    const float* snum = (const float*)d_in[3];
    const float* gnum = (const float*)d_in[4];
    float* out = (float*)d_out;
    char*  ws  = (char*)d_ws;
    int*   ws_scnt    = (int*)(ws + WS_SCNT);
    float* ws_gsum    = (float*)(ws + WS_GSUM);
    float* ws_gcnt    = (float*)(ws + WS_GCNT);
    int*   ws_offs    = (int*)(ws + WS_OFFS);
    int*   ws_curs    = (int*)(ws + WS_CURS);
    int*   ws_rowcode = (int*)(ws + WS_ROWCODE);
    int*   ws_bucket  = (int*)(ws + WS_BUCKET);
    _Float16* cbh = (_Float16*)(ws + WS_CBHI);
    _Float16* cbl = (_Float16*)(ws + WS_CBLO);

    hipMemsetAsync(d_ws, 0, WS_ZERO_BYTES, stream);
    k_convert_cb<<<1024, 256, 0, stream>>>(cb, cbh, cbl);
    k_main<<<NROWS / TM, 256, 0, stream>>>(x, cb, gcb, cbh, cbl,
                                           ws_scnt, ws_gsum, ws_gcnt, ws_rowcode, out);
    k_scan<<<1, 1024, 0, stream>>>(ws_scnt, ws_offs, ws_curs);
    k_scatter<<<(NROWS + 255) / 256, 256, 0, stream>>>(ws_rowcode, ws_curs, ws_bucket);
    k_reduce<<<KCB + 1, 256, 0, stream>>>(x, cb, gcb, snum, gnum,
                                          ws_scnt, ws_offs, ws_bucket,
                                          ws_gsum, ws_gcnt, out);
}

// Round 5
// 245.694 us; speedup vs baseline: 3.5399x; 3.5399x over previous
//
#include <hip/hip_runtime.h>
#include <math.h>

// ---------------- problem constants ----------------
#define NROWS 48000
#define DIM   256
#define KCB   1024
#define GK    64
#define TM    192     // rows per block in K1 (4 waves x 3 sets x 16 rows)
#define NCH   64      // chunks of 16 codes

// ---------------- workspace byte offsets ----------------
#define WS_SCNT    0u         // int[1024]
#define WS_GSUM    4096u      // float[64]
#define WS_GCNT    4352u      // float[64]
#define WS_OFFS    4608u      // int[1024]
#define WS_CURS    8704u      // int[1024]
#define WS_ROWCODE 12800u     // int[48000]
#define WS_BUCKET  204800u    // int[48000]
#define WS_CBHI    396800u    // _Float16[1024*256] swizzled (512 KB)
#define WS_CBLO    921088u    // _Float16[1024*256] swizzled (512 KB)
#define WS_ZERO_BYTES 4608u

// ---------------- output element offsets ----------------
#define OUT_SHAPE 12288000
#define OUT_GAIN  12550144
#define OUT_SNUM  12550208
#define OUT_GNUM  12551232

typedef _Float16 half8  __attribute__((ext_vector_type(8)));
typedef float    f32x4  __attribute__((ext_vector_type(4)));

// K0: split fp32 codebook into f16 hi/lo planes, pre-swizzled into MFMA
// B-fragment order for 16-code chunks: each (chunk,kk) fragment is one
// contiguous, perfectly-coalesced 1024 B wave-load.
// dst(halfs) = ch*4096 + kk*512 + lc*32 + lq*8 + e,
// where code = ch*16+lc, k = kk*32 + lq*8 + e.
__global__ __launch_bounds__(256) void k_convert_cb(const float* __restrict__ cb,
                                                    _Float16* __restrict__ hi,
                                                    _Float16* __restrict__ lo) {
    int i = blockIdx.x * 256 + threadIdx.x;   // 262144 total
    float v = cb[i];
    int code = i >> 8, k = i & 255;
    int ch = code >> 4, lc = code & 15;
    int kk = k >> 5, lq = (k & 31) >> 3, e = k & 7;
    int dst = ch * 4096 + kk * 512 + lc * 32 + lq * 8 + e;
    _Float16 h = (_Float16)v;
    hi[dst] = h;
    lo[dst] = (_Float16)(v - (float)h);
}

// K1: single-generation, barrier-free K-loop. 192 rows/block held as
// register A-fragments (3 sets/wave). B codebook streamed global->VGPR once
// per block; the 4 waves read identical addresses so L1 dedupes the misses.
__global__ __launch_bounds__(256, 1) void k_main(
    const float* __restrict__ x, const float* __restrict__ cb,
    const float* __restrict__ gcb,
    const _Float16* __restrict__ cbh, const _Float16* __restrict__ cbl,
    int* __restrict__ ws_scnt, float* __restrict__ ws_gsum,
    float* __restrict__ ws_gcnt, int* __restrict__ ws_rowcode,
    float* __restrict__ out_q) {
    __shared__ float gl[GK];
    __shared__ int   shInd[TM];
    __shared__ float shGq[TM];
    __shared__ float shLg[TM];
    __shared__ float shGs[GK];   // per-block gain log-sum bins
    __shared__ float shGc[GK];   // per-block gain count bins
    const int tid = threadIdx.x;
    const int w = tid >> 6, lane = tid & 63;
    const int lc = lane & 15, lq = lane >> 4;
    const int row0 = blockIdx.x * TM;

    if (tid < GK) {
        gl[tid] = gcb[tid];
        shGs[tid] = 0.0f;
        shGc[tid] = 0.0f;
    }

    // ---- load + convert A fragments: 3 sets of 16 rows per wave ----
    half8 afh[3][8], afl[3][8];
#pragma unroll
    for (int s = 0; s < 3; ++s) {
        const float* rp = x + (long)(row0 + w * 48 + s * 16 + lc) * DIM + lq * 8;
#pragma unroll
        for (int kk = 0; kk < 8; ++kk) {
            float4 v0 = *(const float4*)(rp + kk * 32);
            float4 v1 = *(const float4*)(rp + kk * 32 + 4);
            _Float16 h0 = (_Float16)v0.x, h1 = (_Float16)v0.y,
                     h2 = (_Float16)v0.z, h3 = (_Float16)v0.w;
            _Float16 h4 = (_Float16)v1.x, h5 = (_Float16)v1.y,
                     h6 = (_Float16)v1.z, h7 = (_Float16)v1.w;
            afh[s][kk] = (half8){h0, h1, h2, h3, h4, h5, h6, h7};
            afl[s][kk] = (half8){(_Float16)(v0.x - (float)h0), (_Float16)(v0.y - (float)h1),
                                 (_Float16)(v0.z - (float)h2), (_Float16)(v0.w - (float)h3),
                                 (_Float16)(v1.x - (float)h4), (_Float16)(v1.y - (float)h5),
                                 (_Float16)(v1.z - (float)h6), (_Float16)(v1.w - (float)h7)};
        }
    }

    float vmax[3][4];
    int   vidx[3][4];
#pragma unroll
    for (int s = 0; s < 3; ++s)
#pragma unroll
        for (int r = 0; r < 4; ++r) { vmax[s][r] = -1e30f; vidx[s][r] = 0; }

    // ---- K-loop: 64 chunks of 16 codes, register-double-buffered B ----
    const half8* pH = (const half8*)(cbh + lc * 32 + lq * 8);  // + ch*512 + kk*64
    const half8* pL = (const half8*)(cbl + lc * 32 + lq * 8);

    half8 b0h[8], b0l[8], b1h[8], b1l[8];
#pragma unroll
    for (int kk = 0; kk < 8; ++kk) {     // load chunk 0 -> buf0
        b0h[kk] = pH[kk * 64];
        b0l[kk] = pL[kk * 64];
    }

    for (int ch = 0; ch < NCH; ch += 2) {
        // issue loads for chunk ch+1 -> buf1 (always valid: ch+1 <= 63)
#pragma unroll
        for (int kk = 0; kk < 8; ++kk) {
            b1h[kk] = pH[(ch + 1) * 512 + kk * 64];
            b1l[kk] = pL[(ch + 1) * 512 + kk * 64];
        }
        // compute on buf0 (chunk ch)
        {
            f32x4 a0[3], a1[3], a2[3];
#pragma unroll
            for (int s = 0; s < 3; ++s) {
                a0[s] = (f32x4){0, 0, 0, 0};
                a1[s] = (f32x4){0, 0, 0, 0};
                a2[s] = (f32x4){0, 0, 0, 0};
            }
#pragma unroll
            for (int kk = 0; kk < 8; ++kk)
#pragma unroll
                for (int s = 0; s < 3; ++s) {
                    a0[s] = __builtin_amdgcn_mfma_f32_16x16x32_f16(afh[s][kk], b0h[kk], a0[s], 0, 0, 0);
                    a1[s] = __builtin_amdgcn_mfma_f32_16x16x32_f16(afl[s][kk], b0h[kk], a1[s], 0, 0, 0);
                    a2[s] = __builtin_amdgcn_mfma_f32_16x16x32_f16(afh[s][kk], b0l[kk], a2[s], 0, 0, 0);
                }
            int code = ch * 16 + lc;
#pragma unroll
            for (int s = 0; s < 3; ++s)
#pragma unroll
                for (int r = 0; r < 4; ++r) {
                    float dv = a0[s][r] + a1[s][r] + a2[s][r];
                    if (dv > vmax[s][r]) { vmax[s][r] = dv; vidx[s][r] = code; }
                }
        }
        // issue loads for chunk ch+2 -> buf0 (guarded)
        if (ch + 2 < NCH) {
#pragma unroll
            for (int kk = 0; kk < 8; ++kk) {
                b0h[kk] = pH[(ch + 2) * 512 + kk * 64];
                b0l[kk] = pL[(ch + 2) * 512 + kk * 64];
            }
        }
        // compute on buf1 (chunk ch+1)
        {
            f32x4 a0[3], a1[3], a2[3];
#pragma unroll
            for (int s = 0; s < 3; ++s) {
                a0[s] = (f32x4){0, 0, 0, 0};
                a1[s] = (f32x4){0, 0, 0, 0};
                a2[s] = (f32x4){0, 0, 0, 0};
            }
#pragma unroll
            for (int kk = 0; kk < 8; ++kk)
#pragma unroll
                for (int s = 0; s < 3; ++s) {
                    a0[s] = __builtin_amdgcn_mfma_f32_16x16x32_f16(afh[s][kk], b1h[kk], a0[s], 0, 0, 0);
                    a1[s] = __builtin_amdgcn_mfma_f32_16x16x32_f16(afl[s][kk], b1h[kk], a1[s], 0, 0, 0);
                    a2[s] = __builtin_amdgcn_mfma_f32_16x16x32_f16(afh[s][kk], b1l[kk], a2[s], 0, 0, 0);
                }
            int code = (ch + 1) * 16 + lc;
#pragma unroll
            for (int s = 0; s < 3; ++s)
#pragma unroll
                for (int r = 0; r < 4; ++r) {
                    float dv = a0[s][r] + a1[s][r] + a2[s][r];
                    if (dv > vmax[s][r]) { vmax[s][r] = dv; vidx[s][r] = code; }
                }
        }
    }

    // ---- argmax reduce across the 16-lane col (lc) dimension ----
#pragma unroll
    for (int m = 1; m < 16; m <<= 1) {
#pragma unroll
        for (int s = 0; s < 3; ++s)
#pragma unroll
            for (int r = 0; r < 4; ++r) {
                float ov = __shfl_xor(vmax[s][r], m, 64);
                int   oi = __shfl_xor(vidx[s][r], m, 64);
                if (ov > vmax[s][r] || (ov == vmax[s][r] && oi < vidx[s][r])) {
                    vmax[s][r] = ov; vidx[s][r] = oi;
                }
            }
    }
    if (lc == 0) {
#pragma unroll
        for (int s = 0; s < 3; ++s)
#pragma unroll
            for (int r = 0; r < 4; ++r) {
                int lrow = w * 48 + s * 16 + lq * 4 + r;
                shLg[lrow]  = vmax[s][r];
                shInd[lrow] = vidx[s][r];
            }
    }
    __syncthreads();

    // ---- parallel gain quantization: lane j evaluates level j ----
    {
        float glv = gl[lane];
        for (int i = 0; i < 48; ++i) {
            int row = w * 48 + i;
            float gv = shLg[row];
            float lg = logf(fmaxf(gv, 1e-5f));
            float d = lg - glv; d = d * d;
            int gi = lane;
#pragma unroll
            for (int m = 1; m < 64; m <<= 1) {
                float od = __shfl_xor(d, m, 64);
                int   og = __shfl_xor(gi, m, 64);
                if (od < d || (od == d && og < gi)) { d = od; gi = og; }
            }
            if (lane == i) {
                float gsel = gl[gi];
                shGq[row] = expf(gsel);
                int sidx = shInd[row];
                ws_rowcode[row0 + row] = sidx;
                atomicAdd(ws_scnt + sidx, 1);
                atomicAdd(shGs + gi, lg);     // LDS pre-aggregation
                atomicAdd(shGc + gi, 1.0f);
            }
        }
    }
    __syncthreads();
    if (tid < GK) {
        if (shGc[tid] != 0.0f) {
            atomicAdd(ws_gsum + tid, shGs[tid]);
            atomicAdd(ws_gcnt + tid, shGc[tid]);
        }
    }

    // ---- epilogue: quantize = exp(gain_q) * cb[code] ----
    {
        float4* qv = (float4*)(out_q + (long)row0 * DIM);
#pragma unroll
        for (int it = 0; it < 48; ++it) {
            int idx = it * 256 + tid;       // 12288 float4s
            int r = idx >> 6, c4 = idx & 63;
            int code = shInd[r];
            float gq = shGq[r];
            const float4 cbv = *(const float4*)(cb + code * DIM + c4 * 4);
            float4 o;
            o.x = gq * cbv.x; o.y = gq * cbv.y; o.z = gq * cbv.z; o.w = gq * cbv.w;
            qv[idx] = o;
        }
    }
}

// K2a: exclusive prefix scan of code counts -> bucket offsets + cursors
__global__ __launch_bounds__(1024) void k_scan(const int* __restrict__ scnt,
                                               int* __restrict__ offs,
                                               int* __restrict__ curs) {
    int t = threadIdx.x;
    __shared__ int sc[1024];
    int my = scnt[t];
    sc[t] = my;
    __syncthreads();
    for (int d = 1; d < 1024; d <<= 1) {
        int v = (t >= d) ? sc[t - d] : 0;
        __syncthreads();
        sc[t] += v;
        __syncthreads();
    }
    int ex = sc[t] - my;
    offs[t] = ex;
    curs[t] = ex;
}

// K2b: scatter row ids into code-sorted buckets
__global__ __launch_bounds__(256) void k_scatter(const int* __restrict__ rowcode,
                                                 int* __restrict__ curs,
                                                 int* __restrict__ bucket) {
    int i = blockIdx.x * 256 + threadIdx.x;
    if (i < NROWS) {
        int code = rowcode[i];
        int pos = atomicAdd(curs + code, 1);
        bucket[pos] = i;
    }
}

// K2c: per-code column reduction of x + full shape/gain finalize
__global__ __launch_bounds__(256) void k_reduce(
    const float* __restrict__ x, const float* __restrict__ cb,
    const float* __restrict__ gcb, const float* __restrict__ snum,
    const float* __restrict__ gnum,
    const int* __restrict__ scnt, const int* __restrict__ offs,
    const int* __restrict__ bucket,
    const float* __restrict__ gsum, const float* __restrict__ gcnt,
    float* __restrict__ out) {
    int b = blockIdx.x, t = threadIdx.x;
    if (b < KCB) {
        int cnt = scnt[b], base = offs[b];
        float s = 0.0f;
        int i = 0;
        for (; i + 4 <= cnt; i += 4) {
            int r0 = bucket[base + i], r1 = bucket[base + i + 1];
            int r2 = bucket[base + i + 2], r3 = bucket[base + i + 3];
            float v0 = x[r0 * DIM + t], v1 = x[r1 * DIM + t];
            float v2 = x[r2 * DIM + t], v3 = x[r3 * DIM + t];
            s += v0 + v1 + v2 + v3;
        }
        for (; i < cnt; ++i) {
            int r = bucket[base + i];
            s += x[r * DIM + t];
        }
        __shared__ float red[4];
        int w = t >> 6;
        float v = s * s;
#pragma unroll
        for (int m = 32; m; m >>= 1) v += __shfl_xor(v, m, 64);
        if ((t & 63) == 0) red[w] = v;
        __syncthreads();
        float tot = red[0] + red[1] + red[2] + red[3];
        float sn = s / fmaxf(sqrtf(tot), 1e-5f);
        float u = cb[b * DIM + t] * 0.99f + 0.01f * sn;
        __syncthreads();
        v = u * u;
#pragma unroll
        for (int m = 32; m; m >>= 1) v += __shfl_xor(v, m, 64);
        if ((t & 63) == 0) red[w] = v;
        __syncthreads();
        tot = red[0] + red[1] + red[2] + red[3];
        out[OUT_SHAPE + b * DIM + t] = u / fmaxf(sqrtf(tot), 1e-12f);
        if (t == 0) out[OUT_SNUM + b] = snum[b] * 0.99f + 0.01f * (float)cnt;
    } else if (t < GK) {
        float cnt = gcnt[t];
        float gn  = gsum[t] / fmaxf(cnt, 1e-5f);
        out[OUT_GAIN + t] = gcb[t] * 0.99f + 0.01f * gn;
        out[OUT_GNUM + t] = gnum[t] * 0.99f + 0.01f * cnt;
    }
}

extern "C" void kernel_launch(void* const* d_in, const int* in_sizes, int n_in,
                              void* d_out, int out_size, void* d_ws, size_t ws_size,
                              hipStream_t stream) {
    const float* x    = (const float*)d_in[0];
    const float* cb   = (const float*)d_in[1];
    const float* gcb  = (const float*)d_in[2];
    const float* snum = (const float*)d_in[3];
    const float* gnum = (const float*)d_in[4];
    float* out = (float*)d_out;
    char*  ws  = (char*)d_ws;
    int*   ws_scnt    = (int*)(ws + WS_SCNT);
    float* ws_gsum    = (float*)(ws + WS_GSUM);
    float* ws_gcnt    = (float*)(ws + WS_GCNT);
    int*   ws_offs    = (int*)(ws + WS_OFFS);
    int*   ws_curs    = (int*)(ws + WS_CURS);
    int*   ws_rowcode = (int*)(ws + WS_ROWCODE);
    int*   ws_bucket  = (int*)(ws + WS_BUCKET);
    _Float16* cbh = (_Float16*)(ws + WS_CBHI);
    _Float16* cbl = (_Float16*)(ws + WS_CBLO);

    hipMemsetAsync(d_ws, 0, WS_ZERO_BYTES, stream);
    k_convert_cb<<<1024, 256, 0, stream>>>(cb, cbh, cbl);
    k_main<<<NROWS / TM, 256, 0, stream>>>(x, cb, gcb, cbh, cbl,
                                           ws_scnt, ws_gsum, ws_gcnt, ws_rowcode, out);
    k_scan<<<1, 1024, 0, stream>>>(ws_scnt, ws_offs, ws_curs);
    k_scatter<<<(NROWS + 255) / 256, 256, 0, stream>>>(ws_rowcode, ws_curs, ws_bucket);
    k_reduce<<<KCB + 1, 256, 0, stream>>>(x, cb, gcb, snum, gnum,
                                          ws_scnt, ws_offs, ws_bucket,
                                          ws_gsum, ws_gcnt, out);
}